// Round 21
// baseline (94.098 us; speedup 1.0000x reference)
//
#include <hip/hip_runtime.h>
#include <hip/hip_fp16.h>
#include <stdint.h>

#define HH 224
#define HWD 224
#define HWP (HH*HWD)      // 50176
#define PH 112
#define PW 112
#define PHW (PH*PW)       // 12544
#define FCK 200704
#define KSEG 196

typedef _Float16 f16x8 __attribute__((ext_vector_type(8)));
typedef float f32x4 __attribute__((ext_vector_type(4)));

static __device__ __forceinline__ uint32_t pkh2(float a, float b) {
  __half2 h = __floats2half2_rn(a, b);
  return __builtin_bit_cast(uint32_t, h);
}
static __device__ __forceinline__ f32x4 mfma16(uint4 a, uint4 b, f32x4 c) {
  return __builtin_amdgcn_mfma_f32_16x16x32_f16(
      __builtin_bit_cast(f16x8, a), __builtin_bit_cast(f16x8, b), c, 0, 0, 0);
}

// ======== MFMA conv template (validated R4-R20) ========
// A (M=16 px along x, K=32 = 2 taps x 16 c): lane l -> px r=l&15, tap parity l>>5,
//   c = ((l>>4)&1)*8 + e.  B: lane l -> o=l&15, same K map.  C/D: o=l&15, px=(l>>4)*4+reg.
// Mask m_j[px,tap] uniform over lane's 8 A elems -> AND-mask on A fragment.
// R21: single-variable disentangle of R19's bundle -- conv2 (256,5)->(256,6)
// ONLY (R20 = R18 base at 87.2us). conv2 LDS 19.7KB permits 8 blocks/CU; the
// bound was binding at 5. VGPR cap at 6 = 85 vs ~75 live. If this regresses,
// R19's fault was conv2@6 and R22 reverts; if it wins, fault was conv1's diet.

// ---------------- pack B-fragment tables (once) ----------------
__global__ __launch_bounds__(256) void pack_wfrags_kernel(
    const float* __restrict__ c1w0, const float* __restrict__ c1w1,
    const float* __restrict__ c1w2, const float* __restrict__ c2w0,
    const float* __restrict__ c2w1, const float* __restrict__ c2w2,
    uint4* __restrict__ wf1, uint4* __restrict__ wf2) {
  int t = blockIdx.x*256 + threadIdx.x;     // grid 8*256 = 2048
  if (t < 960) {                            // conv1 frags
    int ln = t & 63; int pj = t >> 6;
    int p = pj / 3, j = pj % 3;
    int o = ln & 15; int tap = p*2 + (ln >> 5);
    int cbase = ((ln >> 4) & 1) * 8;
    const float* wj = (j == 0) ? c1w0 : (j == 1) ? c1w1 : c1w2;
    float f[8];
    #pragma unroll
    for (int e = 0; e < 8; ++e) {
      int c = cbase + e;
      float v = wj[o*27 + min(c,2)*9 + min(tap,8)];
      f[e] = (tap <= 8 && c < 3) ? v : 0.f;
    }
    wf1[t] = (uint4){ pkh2(f[0],f[1]), pkh2(f[2],f[3]),
                      pkh2(f[4],f[5]), pkh2(f[6],f[7]) };
  } else if (t >= 1024 && t < 1984) {       // conv2 frags
    int tt = t - 1024;
    int ln = tt & 63; int pj = tt >> 6;
    int p = pj / 3, j = pj % 3;
    int o = ln & 15; int tap = p*2 + (ln >> 5);
    int cbase = ((ln >> 4) & 1) * 8;
    const float* wj = (j == 0) ? c2w0 : (j == 1) ? c2w1 : c2w2;
    const float* wp = wj + o*144 + cbase*9 + min(tap,8);
    float f[8];
    #pragma unroll
    for (int e = 0; e < 8; ++e) {
      float v = wp[e*9];
      f[e] = (tap <= 8) ? v : 0.f;
    }
    wf2[tt] = (uint4){ pkh2(f[0],f[1]), pkh2(f[2],f[3]),
                       pkh2(f[4],f[5]), pkh2(f[6],f[7]) };
  }
}

// ---------------- conv1 (+fused sel): 3->16 via MFMA ----------------
__global__ __launch_bounds__(256, 4) void conv1_kernel(
    const float* __restrict__ x, const float* __restrict__ depth,
    const float* __restrict__ fxp, const uint4* __restrict__ wf1,
    const float* __restrict__ bias,
    uint32_t* __restrict__ sel, __half* __restrict__ h1t) {
  __shared__ __align__(16) __half ts[324*24];     // 15552 B  [py][px][c pad 24]
  __shared__ __align__(16) uint4 wlds[15*64];     // 15360 B  B-frags (LDS: invariant)
  __shared__ float dt[324];                       //  1296 B  depth tile (0-filled OOB)
  __shared__ __align__(16) __half hbuf[1024];     //  2048 B  epilogue bounce
  int tid = threadIdx.x;                          // total 34256 B -> 4 blocks/CU
  int lane = tid & 63, wid = tid >> 6;
  int r = lane & 15;
  int tapPar = lane >> 5;
  int c0 = ((lane >> 4) & 1) * 8;
  float bo = bias[r];
  float fx = fxp[0];

  // ---- stage B-frags: coalesced COPY from packed table ----
  #pragma unroll
  for (int it = 0; it < 4; ++it) {
    int t = tid + it*256;
    if (t < 960) wlds[t] = wf1[t];
  }

  int bsw = (blockIdx.x & 7)*196 + (blockIdx.x >> 3);  // XCD swizzle, 1568 = 8*196
  int tbase = bsw * 2;
  float pf[2][3]; float pd[2];
  {
    int tile = tbase;
    int n = tile/196, rem = tile%196, br = rem/14, bc = rem%14;
    int y0 = br*16 - 1, x0 = bc*16 - 1;
    const float* xn = x + (size_t)n*3*HWP;
    const float* dn = depth + (size_t)n*HWP;
    #pragma unroll
    for (int it = 0; it < 2; ++it) {
      int p = min(tid + it*256, 323);
      int yy = y0 + p/18, xx = x0 + p%18;
      int gy = min(max(yy,0),HH-1), gx = min(max(xx,0),HWD-1);
      size_t off = (size_t)gy*HWD + gx;
      pf[it][0] = xn[off]; pf[it][1] = xn[HWP+off]; pf[it][2] = xn[2*HWP+off];
      float dv = dn[off];
      pd[it] = (yy>=0 && yy<HH && xx>=0 && xx<HWD) ? dv : 0.f;  // true 0-pad
    }
  }

  for (int ti = 0; ti < 2; ++ti) {
    int tile = tbase + ti;
    int n = tile/196, rem = tile%196, br = rem/14, bc = rem%14;
    #pragma unroll
    for (int it = 0; it < 2; ++it) {
      int p = tid + it*256;
      if (p < 324) {
        uint4 v0 = { pkh2(pf[it][0], pf[it][1]), pkh2(pf[it][2], 0.f), 0u, 0u };
        uint4 z  = { 0u, 0u, 0u, 0u };
        *(uint4*)(ts + p*24)      = v0;
        *(uint4*)(ts + p*24 + 8)  = z;
        *(uint4*)(ts + p*24 + 16) = z;
        dt[p] = pd[it];
      }
    }
    if (ti < 1) {
      int tile2 = tile + 1;
      int n2 = tile2/196, rem2 = tile2%196, br2 = rem2/14, bc2 = rem2%14;
      int y0 = br2*16 - 1, x0 = bc2*16 - 1;
      const float* xn = x + (size_t)n2*3*HWP;
      const float* dn = depth + (size_t)n2*HWP;
      #pragma unroll
      for (int it = 0; it < 2; ++it) {
        int p = min(tid + it*256, 323);
        int yy = y0 + p/18, xx = x0 + p%18;
        int gy = min(max(yy,0),HH-1), gx = min(max(xx,0),HWD-1);
        size_t off = (size_t)gy*HWD + gx;
        pf[it][0] = xn[off]; pf[it][1] = xn[HWP+off]; pf[it][2] = xn[2*HWP+off];
        float dv = dn[off];
        pd[it] = (yy>=0 && yy<HH && xx>=0 && xx<HWD) ? dv : 0.f;
      }
    }
    __syncthreads();                                 // bar_A: ts/dt (and wlds) ready
    // ---- sel bits: each thread computes its pixel; exchange via intra-wave shfl ----
    uint32_t bits = 0;
    {
      int py = tid >> 4, px = tid & 15;
      float c = dt[(py+1)*18 + (px+1)];
      float gr = c / fx;
      float hf = gr * 0.5f;
      #pragma unroll
      for (int i = 0; i < 3; ++i)
        #pragma unroll
        for (int j = 0; j < 3; ++j) {
          float d = dt[(py+i)*18 + (px+j)];
          int k = i*3 + j;
          uint32_t bb = 0;
          if (fabsf(d - (c + gr)) <= hf) bb |= 1u;
          if (fabsf(d - c) < hf)         bb |= 2u;
          if (fabsf(d - (c - gr)) <= hf) bb |= 4u;
          bits |= bb << (3*k);
        }
      sel[(size_t)n*HWP + (br*16 + py)*HWD + bc*16 + px] = bits;  // for conv2
    }
    uint32_t svc[4];
    #pragma unroll
    for (int ty = 0; ty < 4; ++ty)
      svc[ty] = __shfl(bits, ty*16 + r, 64);         // producer lane ty*16+r, same wave
    // ---- MFMA phase ----
    f32x4 acc[4] = {{0,0,0,0},{0,0,0,0},{0,0,0,0},{0,0,0,0}};
    #pragma unroll
    for (int p = 0; p < 5; ++p) {
      int ta = 2*p, tb = (2*p+1 > 8) ? 8 : 2*p+1;   // tap9 dups tap8 (B=0 kills it)
      int dyL = tapPar ? tb/3 : ta/3;
      int dxL = tapPar ? tb%3 : ta%3;
      int shL = 3*(tapPar ? 2*p+1 : 2*p);
      uint4 a[4];
      #pragma unroll
      for (int ty = 0; ty < 4; ++ty) {
        int ly = wid*4 + ty;
        a[ty] = *(const uint4*)(ts + ((ly + dyL)*18 + (r + dxL))*24 + c0);
      }
      #pragma unroll
      for (int j = 0; j < 3; ++j) {
        uint4 bf = wlds[(p*3 + j)*64 + lane];
        #pragma unroll
        for (int ty = 0; ty < 4; ++ty) {
          uint32_t msk = 0u - ((svc[ty] >> (shL + j)) & 1u);
          uint4 am = { a[ty].x & msk, a[ty].y & msk, a[ty].z & msk, a[ty].w & msk };
          acc[ty] = mfma16(am, bf, acc[ty]);
        }
      }
    }
    // ---- epilogue: relu + channel-last f16 store via hbuf bounce ----
    #pragma unroll
    for (int ty = 0; ty < 4; ++ty) {
      int gy = br*16 + wid*4 + ty;
      #pragma unroll
      for (int e = 0; e < 4; ++e) {
        float v = fmaxf(acc[ty][e] + bo, 0.f);
        hbuf[wid*256 + ((lane>>4)*4 + e)*16 + r] = __float2half(v);
      }
      uint2 hw = *(uint2*)&hbuf[wid*256 + lane*4];
      *(uint2*)(h1t + ((size_t)(n*HWP + gy*HWD) + bc*16)*16 + lane*4) = hw;
    }
    __syncthreads();   // bar_B: ts/dt/hbuf reads done before next tile's writes
  }
}

// ---------------- conv2: 16->16 via MFMA, A-frags DIRECT from global ----------------
__global__ __launch_bounds__(256, 6) void conv2_kernel(
    const __half* __restrict__ h1t, const uint32_t* __restrict__ sel,
    const uint4* __restrict__ wf2, const float* __restrict__ bias,
    __half* __restrict__ pooled) {
  __shared__ __align__(16) uint4 wlds[15*64];     // 15360 B (LDS: invariant)
  __shared__ float pl[64*17];                     //  4352 B -> total 19.7 KB
  int tid = threadIdx.x;
  int lane = tid & 63, wid = tid >> 6;
  int r = lane & 15;
  int tapPar = lane >> 5;
  int c0 = ((lane >> 4) & 1) * 8;
  float bo = bias[r];

  // ---- stage B-frags: coalesced COPY from packed table ----
  #pragma unroll
  for (int it = 0; it < 4; ++it) {
    int t = tid + it*256;
    if (t < 960) wlds[t] = wf2[t];
  }
  __syncthreads();

  int bsw = (blockIdx.x & 7)*196 + (blockIdx.x >> 3);  // same swizzle as conv1
  int tbase = bsw * 2;
  for (int ti = 0; ti < 2; ++ti) {
    int tile = tbase + ti;
    int n = tile/196, rem = tile%196, br = rem/14, bc = rem%14;
    const __half* hn = h1t + (size_t)n*HWP*16;
    uint32_t svc[4];
    #pragma unroll
    for (int ty = 0; ty < 4; ++ty)
      svc[ty] = sel[(size_t)n*HWP + (br*16 + wid*4 + ty)*HWD + bc*16 + r];
    f32x4 acc[4] = {{0,0,0,0},{0,0,0,0},{0,0,0,0},{0,0,0,0}};
    #pragma unroll
    for (int p = 0; p < 5; ++p) {
      int ta = 2*p, tb = (2*p+1 > 8) ? 8 : 2*p+1;
      int dyL = tapPar ? tb/3 : ta/3;
      int dxL = tapPar ? tb%3 : ta%3;
      int shL = 3*(tapPar ? 2*p+1 : 2*p);
      int gx = min(max(bc*16 + r + dxL - 1, 0), HWD-1);
      uint4 a[4];
      #pragma unroll
      for (int ty = 0; ty < 4; ++ty) {
        int gy = min(max(br*16 + wid*4 + ty + dyL - 1, 0), HH-1);
        a[ty] = *(const uint4*)(hn + ((size_t)(gy*HWD + gx))*16 + c0);
      }
      #pragma unroll
      for (int j = 0; j < 3; ++j) {
        uint4 bf = wlds[(p*3 + j)*64 + lane];
        #pragma unroll
        for (int ty = 0; ty < 4; ++ty) {
          uint32_t msk = 0u - ((svc[ty] >> (shL + j)) & 1u);
          uint4 am = { a[ty].x & msk, a[ty].y & msk, a[ty].z & msk, a[ty].w & msk };
          acc[ty] = mfma16(am, bf, acc[ty]);
        }
      }
    }
    #pragma unroll
    for (int yp = 0; yp < 2; ++yp) {
      f32x4 v0 = acc[yp*2], v1 = acc[yp*2+1];
      float m00 = fmaxf(fmaxf(v0[0]+bo, 0.f), fmaxf(v0[1]+bo, 0.f));
      float m01 = fmaxf(fmaxf(v0[2]+bo, 0.f), fmaxf(v0[3]+bo, 0.f));
      float m10 = fmaxf(fmaxf(v1[0]+bo, 0.f), fmaxf(v1[1]+bo, 0.f));
      float m11 = fmaxf(fmaxf(v1[2]+bo, 0.f), fmaxf(v1[3]+bo, 0.f));
      int prow = wid*2 + yp;
      int pc0 = (lane >> 4)*2;
      pl[(prow*8 + pc0)*17 + r]     = fmaxf(m00, m10);
      pl[(prow*8 + pc0 + 1)*17 + r] = fmaxf(m01, m11);
    }
    __syncthreads();   // pl ready
    for (int t = tid; t < 1024; t += 256) {       // repack channel-first f16
      int oo = t >> 6; int pix = t & 63;
      int pr = pix >> 3, pc = pix & 7;
      pooled[(size_t)(n*16 + oo)*PHW + (br*8 + pr)*PW + bc*8 + pc] =
          __float2half(pl[pix*17 + oo]);
    }
    __syncthreads();   // pl reads done before next tile's writes
  }
}

// ---------------- FC1 via MFMA: fragments DIRECT from global, barrier-free K-loop ----------------
__global__ __launch_bounds__(256) void fc1_kernel(
    const __half* __restrict__ hin, const float* __restrict__ wgt,
    float* __restrict__ partial) {
  __shared__ __align__(16) f32x4 cacc[2][256];     //  8 KB
  int tid = threadIdx.x;
  int b = blockIdx.x;
  int snum = (b & 7)*98 + (b >> 3);   // bijective XCD swizzle: 784 = 8 * 98
  int kseg = snum >> 2;
  int grp  = snum & 3;
  int obase = grp * 32;
  int lane = tid & 63, wid = tid >> 6;
  int row = lane & 15;
  int koct = lane >> 4;               // 0..3 -> k-octet within K=32
  size_t kb = (size_t)kseg*1024 + wid*256 + koct*8;
  const __half* ap  = hin + (size_t)row*FCK + kb;
  const float*  wp0 = wgt + (size_t)(obase + row)*FCK + kb;
  const float*  wp1 = wp0 + (size_t)16*FCK;
  f32x4 acc0 = {0,0,0,0}, acc1 = {0,0,0,0};
  #pragma unroll
  for (int s = 0; s < 8; ++s) {
    uint4 av = *(const uint4*)(ap + s*32);
    float4 wa = *(const float4*)(wp0 + s*32);
    float4 wb = *(const float4*)(wp0 + s*32 + 4);
    float4 wc = *(const float4*)(wp1 + s*32);
    float4 wd = *(const float4*)(wp1 + s*32 + 4);
    uint4 bf0 = { pkh2(wa.x,wa.y), pkh2(wa.z,wa.w), pkh2(wb.x,wb.y), pkh2(wb.z,wb.w) };
    uint4 bf1 = { pkh2(wc.x,wc.y), pkh2(wc.z,wc.w), pkh2(wd.x,wd.y), pkh2(wd.z,wd.w) };
    acc0 = mfma16(av, bf0, acc0);
    acc1 = mfma16(av, bf1, acc1);
  }
  cacc[0][wid*64 + lane] = acc0;
  cacc[1][wid*64 + lane] = acc1;
  __syncthreads();
  {
    int l = tid & 63, e = tid >> 6;
    int nn = (l >> 4)*4 + e;
    int oo = l & 15;
    #pragma unroll
    for (int g = 0; g < 2; ++g) {
      float s = cacc[g][l][e] + cacc[g][64 + l][e] + cacc[g][128 + l][e] + cacc[g][192 + l][e];
      partial[((size_t)kseg*16 + nn)*128 + obase + g*16 + oo] = s;
    }
  }
}

// ---------------- FC2 (+fused fc1-reduce) + log_softmax, 1024 threads ----------------
__global__ __launch_bounds__(1024) void fc2_kernel(
    const float* __restrict__ partial, const float* __restrict__ fc1b,
    const float* __restrict__ w, const float* __restrict__ b,
    float* __restrict__ out) {
  __shared__ float psum[1024];
  __shared__ float row[128];
  __shared__ float v[10];
  __shared__ float lse;
  int n = blockIdx.x, t = threadIdx.x;
  {
    int o = t & 127, slice = t >> 7;              // 8 slices
    const float* pp = partial + ((size_t)slice*16 + n)*128 + o;
    float s = 0.f;
    for (int k = slice; k < KSEG; k += 8)
      s += pp[(size_t)(k - slice)*2048];
    psum[t] = s;
  }
  __syncthreads();
  if (t < 128) {
    float s = fc1b[t];
    #pragma unroll
    for (int sl = 0; sl < 8; ++sl) s += psum[sl*128 + t];
    row[t] = s;
  }
  __syncthreads();
  {
    int wv = t >> 6, lane = t & 63;
    if (wv < 10) {
      int d = wv;
      float acc = w[d*128 + lane]*row[lane] + w[d*128 + 64 + lane]*row[64 + lane];
      acc += __shfl_xor(acc, 1);  acc += __shfl_xor(acc, 2);
      acc += __shfl_xor(acc, 4);  acc += __shfl_xor(acc, 8);
      acc += __shfl_xor(acc, 16); acc += __shfl_xor(acc, 32);
      if (lane == 0) v[d] = acc + b[d];
    }
  }
  __syncthreads();
  if (t == 0) {
    float m = v[0];
    for (int i = 1; i < 10; ++i) m = fmaxf(m, v[i]);
    float se = 0.f;
    for (int i = 0; i < 10; ++i) se += expf(v[i] - m);
    lse = m + logf(se);
  }
  __syncthreads();
  if (t < 10) out[n*10 + t] = v[t] - lse;
}

extern "C" void kernel_launch(void* const* d_in, const int* in_sizes, int n_in,
                              void* d_out, int out_size, void* d_ws, size_t ws_size,
                              hipStream_t stream) {
  const float* x     = (const float*)d_in[0];
  const float* depth = (const float*)d_in[1];
  const float* fx    = (const float*)d_in[2];
  const float* c1w0  = (const float*)d_in[3];
  const float* c1w1  = (const float*)d_in[4];
  const float* c1w2  = (const float*)d_in[5];
  const float* c1b   = (const float*)d_in[6];
  const float* c2w0  = (const float*)d_in[7];
  const float* c2w1  = (const float*)d_in[8];
  const float* c2w2  = (const float*)d_in[9];
  const float* c2b   = (const float*)d_in[10];
  const float* fc1w  = (const float*)d_in[11];
  const float* fc1b  = (const float*)d_in[12];
  const float* fc2w  = (const float*)d_in[13];
  const float* fc2b  = (const float*)d_in[14];
  float* out = (float*)d_out;

  char* ws = (char*)d_ws;
  uint32_t* sel  = (uint32_t*)ws;                      // 3,211,264 B
  __half* h1t    = (__half*)(ws + 3211264);            // 25,690,112 B
  __half* pooled = (__half*)(ws + 28901376);           //  6,422,528 B
  float* partial = (float*)(ws + 35323904);            //  1,605,632 B
  uint4* wf1     = (uint4*)(ws + 36929536);            //     15,360 B
  uint4* wf2     = (uint4*)(ws + 36944896);            //     15,360 B

  pack_wfrags_kernel<<<8, 256, 0, stream>>>(c1w0, c1w1, c1w2, c2w0, c2w1, c2w2, wf1, wf2);
  conv1_kernel<<<1568, 256, 0, stream>>>(x, depth, fx, wf1, c1b, sel, h1t);
  conv2_kernel<<<1568, 256, 0, stream>>>(h1t, sel, wf2, c2b, pooled);
  fc1_kernel<<<784, 256, 0, stream>>>(pooled, fc1w, partial);
  fc2_kernel<<<16, 1024, 0, stream>>>(partial, fc1b, fc2w, fc2b, out);
}

// Round 22
// 87.649 us; speedup vs baseline: 1.0736x; 1.0736x over previous
//
#include <hip/hip_runtime.h>
#include <hip/hip_fp16.h>
#include <stdint.h>

#define HH 224
#define HWD 224
#define HWP (HH*HWD)      // 50176
#define PH 112
#define PW 112
#define PHW (PH*PW)       // 12544
#define FCK 200704
#define KSEG 196

typedef _Float16 f16x8 __attribute__((ext_vector_type(8)));
typedef float f32x4 __attribute__((ext_vector_type(4)));

static __device__ __forceinline__ uint32_t pkh2(float a, float b) {
  __half2 h = __floats2half2_rn(a, b);
  return __builtin_bit_cast(uint32_t, h);
}
static __device__ __forceinline__ f32x4 mfma16(uint4 a, uint4 b, f32x4 c) {
  return __builtin_amdgcn_mfma_f32_16x16x32_f16(
      __builtin_bit_cast(f16x8, a), __builtin_bit_cast(f16x8, b), c, 0, 0, 0);
}

// ======== MFMA conv template (validated R4-R21) ========
// A (M=16 px along x, K=32 = 2 taps x 16 c): lane l -> px r=l&15, tap parity l>>5,
//   c = ((l>>4)&1)*8 + e.  B: lane l -> o=l&15, same K map.  C/D: o=l&15, px=(l>>4)*4+reg.
// Mask m_j[px,tap] uniform over lane's 8 A elems -> AND-mask on A fragment.
// R22 FINAL: exact R20/R18 configuration (87.2us, twice-reproduced best).
// R21 isolated conv2@(256,6) as +6.9us (VGPR-cap spill at 85); R19's conv1 diet
// also independently harmful. Occupancy optimum mapped: conv1@4, conv2@5.
// Keepers: packed B-frag tables + coalesced LDS copy (cheap blocks),
// tiles/block=2 grid 1568, shfl sel-exchange, XCD swizzles, direct-global
// A-frags (conv2) and A/B-frags (fc1, barrier-free), parallel fc2.

// ---------------- pack B-fragment tables (once) ----------------
__global__ __launch_bounds__(256) void pack_wfrags_kernel(
    const float* __restrict__ c1w0, const float* __restrict__ c1w1,
    const float* __restrict__ c1w2, const float* __restrict__ c2w0,
    const float* __restrict__ c2w1, const float* __restrict__ c2w2,
    uint4* __restrict__ wf1, uint4* __restrict__ wf2) {
  int t = blockIdx.x*256 + threadIdx.x;     // grid 8*256 = 2048
  if (t < 960) {                            // conv1 frags
    int ln = t & 63; int pj = t >> 6;
    int p = pj / 3, j = pj % 3;
    int o = ln & 15; int tap = p*2 + (ln >> 5);
    int cbase = ((ln >> 4) & 1) * 8;
    const float* wj = (j == 0) ? c1w0 : (j == 1) ? c1w1 : c1w2;
    float f[8];
    #pragma unroll
    for (int e = 0; e < 8; ++e) {
      int c = cbase + e;
      float v = wj[o*27 + min(c,2)*9 + min(tap,8)];
      f[e] = (tap <= 8 && c < 3) ? v : 0.f;
    }
    wf1[t] = (uint4){ pkh2(f[0],f[1]), pkh2(f[2],f[3]),
                      pkh2(f[4],f[5]), pkh2(f[6],f[7]) };
  } else if (t >= 1024 && t < 1984) {       // conv2 frags
    int tt = t - 1024;
    int ln = tt & 63; int pj = tt >> 6;
    int p = pj / 3, j = pj % 3;
    int o = ln & 15; int tap = p*2 + (ln >> 5);
    int cbase = ((ln >> 4) & 1) * 8;
    const float* wj = (j == 0) ? c2w0 : (j == 1) ? c2w1 : c2w2;
    const float* wp = wj + o*144 + cbase*9 + min(tap,8);
    float f[8];
    #pragma unroll
    for (int e = 0; e < 8; ++e) {
      float v = wp[e*9];
      f[e] = (tap <= 8) ? v : 0.f;
    }
    wf2[tt] = (uint4){ pkh2(f[0],f[1]), pkh2(f[2],f[3]),
                       pkh2(f[4],f[5]), pkh2(f[6],f[7]) };
  }
}

// ---------------- conv1 (+fused sel): 3->16 via MFMA ----------------
__global__ __launch_bounds__(256, 4) void conv1_kernel(
    const float* __restrict__ x, const float* __restrict__ depth,
    const float* __restrict__ fxp, const uint4* __restrict__ wf1,
    const float* __restrict__ bias,
    uint32_t* __restrict__ sel, __half* __restrict__ h1t) {
  __shared__ __align__(16) __half ts[324*24];     // 15552 B  [py][px][c pad 24]
  __shared__ __align__(16) uint4 wlds[15*64];     // 15360 B  B-frags (LDS: invariant)
  __shared__ float dt[324];                       //  1296 B  depth tile (0-filled OOB)
  __shared__ __align__(16) __half hbuf[1024];     //  2048 B  epilogue bounce
  int tid = threadIdx.x;                          // total 34256 B -> 4 blocks/CU
  int lane = tid & 63, wid = tid >> 6;
  int r = lane & 15;
  int tapPar = lane >> 5;
  int c0 = ((lane >> 4) & 1) * 8;
  float bo = bias[r];
  float fx = fxp[0];

  // ---- stage B-frags: coalesced COPY from packed table ----
  #pragma unroll
  for (int it = 0; it < 4; ++it) {
    int t = tid + it*256;
    if (t < 960) wlds[t] = wf1[t];
  }

  int bsw = (blockIdx.x & 7)*196 + (blockIdx.x >> 3);  // XCD swizzle, 1568 = 8*196
  int tbase = bsw * 2;
  float pf[2][3]; float pd[2];
  {
    int tile = tbase;
    int n = tile/196, rem = tile%196, br = rem/14, bc = rem%14;
    int y0 = br*16 - 1, x0 = bc*16 - 1;
    const float* xn = x + (size_t)n*3*HWP;
    const float* dn = depth + (size_t)n*HWP;
    #pragma unroll
    for (int it = 0; it < 2; ++it) {
      int p = min(tid + it*256, 323);
      int yy = y0 + p/18, xx = x0 + p%18;
      int gy = min(max(yy,0),HH-1), gx = min(max(xx,0),HWD-1);
      size_t off = (size_t)gy*HWD + gx;
      pf[it][0] = xn[off]; pf[it][1] = xn[HWP+off]; pf[it][2] = xn[2*HWP+off];
      float dv = dn[off];
      pd[it] = (yy>=0 && yy<HH && xx>=0 && xx<HWD) ? dv : 0.f;  // true 0-pad
    }
  }

  for (int ti = 0; ti < 2; ++ti) {
    int tile = tbase + ti;
    int n = tile/196, rem = tile%196, br = rem/14, bc = rem%14;
    #pragma unroll
    for (int it = 0; it < 2; ++it) {
      int p = tid + it*256;
      if (p < 324) {
        uint4 v0 = { pkh2(pf[it][0], pf[it][1]), pkh2(pf[it][2], 0.f), 0u, 0u };
        uint4 z  = { 0u, 0u, 0u, 0u };
        *(uint4*)(ts + p*24)      = v0;
        *(uint4*)(ts + p*24 + 8)  = z;
        *(uint4*)(ts + p*24 + 16) = z;
        dt[p] = pd[it];
      }
    }
    if (ti < 1) {
      int tile2 = tile + 1;
      int n2 = tile2/196, rem2 = tile2%196, br2 = rem2/14, bc2 = rem2%14;
      int y0 = br2*16 - 1, x0 = bc2*16 - 1;
      const float* xn = x + (size_t)n2*3*HWP;
      const float* dn = depth + (size_t)n2*HWP;
      #pragma unroll
      for (int it = 0; it < 2; ++it) {
        int p = min(tid + it*256, 323);
        int yy = y0 + p/18, xx = x0 + p%18;
        int gy = min(max(yy,0),HH-1), gx = min(max(xx,0),HWD-1);
        size_t off = (size_t)gy*HWD + gx;
        pf[it][0] = xn[off]; pf[it][1] = xn[HWP+off]; pf[it][2] = xn[2*HWP+off];
        float dv = dn[off];
        pd[it] = (yy>=0 && yy<HH && xx>=0 && xx<HWD) ? dv : 0.f;
      }
    }
    __syncthreads();                                 // bar_A: ts/dt (and wlds) ready
    // ---- sel bits: each thread computes its pixel; exchange via intra-wave shfl ----
    uint32_t bits = 0;
    {
      int py = tid >> 4, px = tid & 15;
      float c = dt[(py+1)*18 + (px+1)];
      float gr = c / fx;
      float hf = gr * 0.5f;
      #pragma unroll
      for (int i = 0; i < 3; ++i)
        #pragma unroll
        for (int j = 0; j < 3; ++j) {
          float d = dt[(py+i)*18 + (px+j)];
          int k = i*3 + j;
          uint32_t bb = 0;
          if (fabsf(d - (c + gr)) <= hf) bb |= 1u;
          if (fabsf(d - c) < hf)         bb |= 2u;
          if (fabsf(d - (c - gr)) <= hf) bb |= 4u;
          bits |= bb << (3*k);
        }
      sel[(size_t)n*HWP + (br*16 + py)*HWD + bc*16 + px] = bits;  // for conv2
    }
    uint32_t svc[4];
    #pragma unroll
    for (int ty = 0; ty < 4; ++ty)
      svc[ty] = __shfl(bits, ty*16 + r, 64);         // producer lane ty*16+r, same wave
    // ---- MFMA phase ----
    f32x4 acc[4] = {{0,0,0,0},{0,0,0,0},{0,0,0,0},{0,0,0,0}};
    #pragma unroll
    for (int p = 0; p < 5; ++p) {
      int ta = 2*p, tb = (2*p+1 > 8) ? 8 : 2*p+1;   // tap9 dups tap8 (B=0 kills it)
      int dyL = tapPar ? tb/3 : ta/3;
      int dxL = tapPar ? tb%3 : ta%3;
      int shL = 3*(tapPar ? 2*p+1 : 2*p);
      uint4 a[4];
      #pragma unroll
      for (int ty = 0; ty < 4; ++ty) {
        int ly = wid*4 + ty;
        a[ty] = *(const uint4*)(ts + ((ly + dyL)*18 + (r + dxL))*24 + c0);
      }
      #pragma unroll
      for (int j = 0; j < 3; ++j) {
        uint4 bf = wlds[(p*3 + j)*64 + lane];
        #pragma unroll
        for (int ty = 0; ty < 4; ++ty) {
          uint32_t msk = 0u - ((svc[ty] >> (shL + j)) & 1u);
          uint4 am = { a[ty].x & msk, a[ty].y & msk, a[ty].z & msk, a[ty].w & msk };
          acc[ty] = mfma16(am, bf, acc[ty]);
        }
      }
    }
    // ---- epilogue: relu + channel-last f16 store via hbuf bounce ----
    #pragma unroll
    for (int ty = 0; ty < 4; ++ty) {
      int gy = br*16 + wid*4 + ty;
      #pragma unroll
      for (int e = 0; e < 4; ++e) {
        float v = fmaxf(acc[ty][e] + bo, 0.f);
        hbuf[wid*256 + ((lane>>4)*4 + e)*16 + r] = __float2half(v);
      }
      uint2 hw = *(uint2*)&hbuf[wid*256 + lane*4];
      *(uint2*)(h1t + ((size_t)(n*HWP + gy*HWD) + bc*16)*16 + lane*4) = hw;
    }
    __syncthreads();   // bar_B: ts/dt/hbuf reads done before next tile's writes
  }
}

// ---------------- conv2: 16->16 via MFMA, A-frags DIRECT from global ----------------
__global__ __launch_bounds__(256, 5) void conv2_kernel(
    const __half* __restrict__ h1t, const uint32_t* __restrict__ sel,
    const uint4* __restrict__ wf2, const float* __restrict__ bias,
    __half* __restrict__ pooled) {
  __shared__ __align__(16) uint4 wlds[15*64];     // 15360 B (LDS: invariant)
  __shared__ float pl[64*17];                     //  4352 B -> total 19.7 KB, 5/CU
  int tid = threadIdx.x;
  int lane = tid & 63, wid = tid >> 6;
  int r = lane & 15;
  int tapPar = lane >> 5;
  int c0 = ((lane >> 4) & 1) * 8;
  float bo = bias[r];

  // ---- stage B-frags: coalesced COPY from packed table ----
  #pragma unroll
  for (int it = 0; it < 4; ++it) {
    int t = tid + it*256;
    if (t < 960) wlds[t] = wf2[t];
  }
  __syncthreads();

  int bsw = (blockIdx.x & 7)*196 + (blockIdx.x >> 3);  // same swizzle as conv1
  int tbase = bsw * 2;
  for (int ti = 0; ti < 2; ++ti) {
    int tile = tbase + ti;
    int n = tile/196, rem = tile%196, br = rem/14, bc = rem%14;
    const __half* hn = h1t + (size_t)n*HWP*16;
    uint32_t svc[4];
    #pragma unroll
    for (int ty = 0; ty < 4; ++ty)
      svc[ty] = sel[(size_t)n*HWP + (br*16 + wid*4 + ty)*HWD + bc*16 + r];
    f32x4 acc[4] = {{0,0,0,0},{0,0,0,0},{0,0,0,0},{0,0,0,0}};
    #pragma unroll
    for (int p = 0; p < 5; ++p) {
      int ta = 2*p, tb = (2*p+1 > 8) ? 8 : 2*p+1;
      int dyL = tapPar ? tb/3 : ta/3;
      int dxL = tapPar ? tb%3 : ta%3;
      int shL = 3*(tapPar ? 2*p+1 : 2*p);
      int gx = min(max(bc*16 + r + dxL - 1, 0), HWD-1);
      uint4 a[4];
      #pragma unroll
      for (int ty = 0; ty < 4; ++ty) {
        int gy = min(max(br*16 + wid*4 + ty + dyL - 1, 0), HH-1);
        a[ty] = *(const uint4*)(hn + ((size_t)(gy*HWD + gx))*16 + c0);
      }
      #pragma unroll
      for (int j = 0; j < 3; ++j) {
        uint4 bf = wlds[(p*3 + j)*64 + lane];
        #pragma unroll
        for (int ty = 0; ty < 4; ++ty) {
          uint32_t msk = 0u - ((svc[ty] >> (shL + j)) & 1u);
          uint4 am = { a[ty].x & msk, a[ty].y & msk, a[ty].z & msk, a[ty].w & msk };
          acc[ty] = mfma16(am, bf, acc[ty]);
        }
      }
    }
    #pragma unroll
    for (int yp = 0; yp < 2; ++yp) {
      f32x4 v0 = acc[yp*2], v1 = acc[yp*2+1];
      float m00 = fmaxf(fmaxf(v0[0]+bo, 0.f), fmaxf(v0[1]+bo, 0.f));
      float m01 = fmaxf(fmaxf(v0[2]+bo, 0.f), fmaxf(v0[3]+bo, 0.f));
      float m10 = fmaxf(fmaxf(v1[0]+bo, 0.f), fmaxf(v1[1]+bo, 0.f));
      float m11 = fmaxf(fmaxf(v1[2]+bo, 0.f), fmaxf(v1[3]+bo, 0.f));
      int prow = wid*2 + yp;
      int pc0 = (lane >> 4)*2;
      pl[(prow*8 + pc0)*17 + r]     = fmaxf(m00, m10);
      pl[(prow*8 + pc0 + 1)*17 + r] = fmaxf(m01, m11);
    }
    __syncthreads();   // pl ready
    for (int t = tid; t < 1024; t += 256) {       // repack channel-first f16
      int oo = t >> 6; int pix = t & 63;
      int pr = pix >> 3, pc = pix & 7;
      pooled[(size_t)(n*16 + oo)*PHW + (br*8 + pr)*PW + bc*8 + pc] =
          __float2half(pl[pix*17 + oo]);
    }
    __syncthreads();   // pl reads done before next tile's writes
  }
}

// ---------------- FC1 via MFMA: fragments DIRECT from global, barrier-free K-loop ----------------
__global__ __launch_bounds__(256) void fc1_kernel(
    const __half* __restrict__ hin, const float* __restrict__ wgt,
    float* __restrict__ partial) {
  __shared__ __align__(16) f32x4 cacc[2][256];     //  8 KB
  int tid = threadIdx.x;
  int b = blockIdx.x;
  int snum = (b & 7)*98 + (b >> 3);   // bijective XCD swizzle: 784 = 8 * 98
  int kseg = snum >> 2;
  int grp  = snum & 3;
  int obase = grp * 32;
  int lane = tid & 63, wid = tid >> 6;
  int row = lane & 15;
  int koct = lane >> 4;               // 0..3 -> k-octet within K=32
  size_t kb = (size_t)kseg*1024 + wid*256 + koct*8;
  const __half* ap  = hin + (size_t)row*FCK + kb;
  const float*  wp0 = wgt + (size_t)(obase + row)*FCK + kb;
  const float*  wp1 = wp0 + (size_t)16*FCK;
  f32x4 acc0 = {0,0,0,0}, acc1 = {0,0,0,0};
  #pragma unroll
  for (int s = 0; s < 8; ++s) {
    uint4 av = *(const uint4*)(ap + s*32);
    float4 wa = *(const float4*)(wp0 + s*32);
    float4 wb = *(const float4*)(wp0 + s*32 + 4);
    float4 wc = *(const float4*)(wp1 + s*32);
    float4 wd = *(const float4*)(wp1 + s*32 + 4);
    uint4 bf0 = { pkh2(wa.x,wa.y), pkh2(wa.z,wa.w), pkh2(wb.x,wb.y), pkh2(wb.z,wb.w) };
    uint4 bf1 = { pkh2(wc.x,wc.y), pkh2(wc.z,wc.w), pkh2(wd.x,wd.y), pkh2(wd.z,wd.w) };
    acc0 = mfma16(av, bf0, acc0);
    acc1 = mfma16(av, bf1, acc1);
  }
  cacc[0][wid*64 + lane] = acc0;
  cacc[1][wid*64 + lane] = acc1;
  __syncthreads();
  {
    int l = tid & 63, e = tid >> 6;
    int nn = (l >> 4)*4 + e;
    int oo = l & 15;
    #pragma unroll
    for (int g = 0; g < 2; ++g) {
      float s = cacc[g][l][e] + cacc[g][64 + l][e] + cacc[g][128 + l][e] + cacc[g][192 + l][e];
      partial[((size_t)kseg*16 + nn)*128 + obase + g*16 + oo] = s;
    }
  }
}

// ---------------- FC2 (+fused fc1-reduce) + log_softmax, 1024 threads ----------------
__global__ __launch_bounds__(1024) void fc2_kernel(
    const float* __restrict__ partial, const float* __restrict__ fc1b,
    const float* __restrict__ w, const float* __restrict__ b,
    float* __restrict__ out) {
  __shared__ float psum[1024];
  __shared__ float row[128];
  __shared__ float v[10];
  __shared__ float lse;
  int n = blockIdx.x, t = threadIdx.x;
  {
    int o = t & 127, slice = t >> 7;              // 8 slices
    const float* pp = partial + ((size_t)slice*16 + n)*128 + o;
    float s = 0.f;
    for (int k = slice; k < KSEG; k += 8)
      s += pp[(size_t)(k - slice)*2048];
    psum[t] = s;
  }
  __syncthreads();
  if (t < 128) {
    float s = fc1b[t];
    #pragma unroll
    for (int sl = 0; sl < 8; ++sl) s += psum[sl*128 + t];
    row[t] = s;
  }
  __syncthreads();
  {
    int wv = t >> 6, lane = t & 63;
    if (wv < 10) {
      int d = wv;
      float acc = w[d*128 + lane]*row[lane] + w[d*128 + 64 + lane]*row[64 + lane];
      acc += __shfl_xor(acc, 1);  acc += __shfl_xor(acc, 2);
      acc += __shfl_xor(acc, 4);  acc += __shfl_xor(acc, 8);
      acc += __shfl_xor(acc, 16); acc += __shfl_xor(acc, 32);
      if (lane == 0) v[d] = acc + b[d];
    }
  }
  __syncthreads();
  if (t == 0) {
    float m = v[0];
    for (int i = 1; i < 10; ++i) m = fmaxf(m, v[i]);
    float se = 0.f;
    for (int i = 0; i < 10; ++i) se += expf(v[i] - m);
    lse = m + logf(se);
  }
  __syncthreads();
  if (t < 10) out[n*10 + t] = v[t] - lse;
}

extern "C" void kernel_launch(void* const* d_in, const int* in_sizes, int n_in,
                              void* d_out, int out_size, void* d_ws, size_t ws_size,
                              hipStream_t stream) {
  const float* x     = (const float*)d_in[0];
  const float* depth = (const float*)d_in[1];
  const float* fx    = (const float*)d_in[2];
  const float* c1w0  = (const float*)d_in[3];
  const float* c1w1  = (const float*)d_in[4];
  const float* c1w2  = (const float*)d_in[5];
  const float* c1b   = (const float*)d_in[6];
  const float* c2w0  = (const float*)d_in[7];
  const float* c2w1  = (const float*)d_in[8];
  const float* c2w2  = (const float*)d_in[9];
  const float* c2b   = (const float*)d_in[10];
  const float* fc1w  = (const float*)d_in[11];
  const float* fc1b  = (const float*)d_in[12];
  const float* fc2w  = (const float*)d_in[13];
  const float* fc2b  = (const float*)d_in[14];
  float* out = (float*)d_out;

  char* ws = (char*)d_ws;
  uint32_t* sel  = (uint32_t*)ws;                      // 3,211,264 B
  __half* h1t    = (__half*)(ws + 3211264);            // 25,690,112 B
  __half* pooled = (__half*)(ws + 28901376);           //  6,422,528 B
  float* partial = (float*)(ws + 35323904);            //  1,605,632 B
  uint4* wf1     = (uint4*)(ws + 36929536);            //     15,360 B
  uint4* wf2     = (uint4*)(ws + 36944896);            //     15,360 B

  pack_wfrags_kernel<<<8, 256, 0, stream>>>(c1w0, c1w1, c1w2, c2w0, c2w1, c2w2, wf1, wf2);
  conv1_kernel<<<1568, 256, 0, stream>>>(x, depth, fx, wf1, c1b, sel, h1t);
  conv2_kernel<<<1568, 256, 0, stream>>>(h1t, sel, wf2, c2b, pooled);
  fc1_kernel<<<784, 256, 0, stream>>>(pooled, fc1w, partial);
  fc2_kernel<<<16, 1024, 0, stream>>>(partial, fc1b, fc2w, fc2b, out);
}

// Round 23
// 85.812 us; speedup vs baseline: 1.0966x; 1.0214x over previous
//
#include <hip/hip_runtime.h>
#include <hip/hip_fp16.h>
#include <stdint.h>

#define HH 224
#define HWD 224
#define HWP (HH*HWD)      // 50176
#define PH 112
#define PW 112
#define PHW (PH*PW)       // 12544
#define FCK 200704
#define KSEG 196

typedef _Float16 f16x8 __attribute__((ext_vector_type(8)));
typedef float f32x4 __attribute__((ext_vector_type(4)));

static __device__ __forceinline__ uint32_t pkh2(float a, float b) {
  __half2 h = __floats2half2_rn(a, b);
  return __builtin_bit_cast(uint32_t, h);
}
static __device__ __forceinline__ f32x4 mfma16(uint4 a, uint4 b, f32x4 c) {
  return __builtin_amdgcn_mfma_f32_16x16x32_f16(
      __builtin_bit_cast(f16x8, a), __builtin_bit_cast(f16x8, b), c, 0, 0, 0);
}

// ======== MFMA conv template (validated R4-R22) ========
// A (M=16 px along x, K=32 = 2 taps x 16 c): lane l -> px r=l&15, tap parity l>>5,
//   c = ((l>>4)&1)*8 + e.  B: lane l -> o=l&15, same K map.  C/D: o=l&15, px=(l>>4)*4+reg.
// Mask m_j[px,tap] uniform over lane's 8 A elems -> AND-mask on A fragment.
// R23: convs/fc2 = R22 (87.x, 3x-reproduced). Single variable: fc1 grid
// 784->1568, 16 outputs/block (was 32) -- the R18 cheap-block residency lever
// applied to the one kernel still at 3.06 blocks/CU. Per-output reduction
// structure unchanged -> bit-identical partials. Swizzle updated (1568=8*196);
// the 8 output-grps of one kseg stay on one XCD (A-slice L2 locality kept).

// ---------------- pack B-fragment tables (once) ----------------
__global__ __launch_bounds__(256) void pack_wfrags_kernel(
    const float* __restrict__ c1w0, const float* __restrict__ c1w1,
    const float* __restrict__ c1w2, const float* __restrict__ c2w0,
    const float* __restrict__ c2w1, const float* __restrict__ c2w2,
    uint4* __restrict__ wf1, uint4* __restrict__ wf2) {
  int t = blockIdx.x*256 + threadIdx.x;     // grid 8*256 = 2048
  if (t < 960) {                            // conv1 frags
    int ln = t & 63; int pj = t >> 6;
    int p = pj / 3, j = pj % 3;
    int o = ln & 15; int tap = p*2 + (ln >> 5);
    int cbase = ((ln >> 4) & 1) * 8;
    const float* wj = (j == 0) ? c1w0 : (j == 1) ? c1w1 : c1w2;
    float f[8];
    #pragma unroll
    for (int e = 0; e < 8; ++e) {
      int c = cbase + e;
      float v = wj[o*27 + min(c,2)*9 + min(tap,8)];
      f[e] = (tap <= 8 && c < 3) ? v : 0.f;
    }
    wf1[t] = (uint4){ pkh2(f[0],f[1]), pkh2(f[2],f[3]),
                      pkh2(f[4],f[5]), pkh2(f[6],f[7]) };
  } else if (t >= 1024 && t < 1984) {       // conv2 frags
    int tt = t - 1024;
    int ln = tt & 63; int pj = tt >> 6;
    int p = pj / 3, j = pj % 3;
    int o = ln & 15; int tap = p*2 + (ln >> 5);
    int cbase = ((ln >> 4) & 1) * 8;
    const float* wj = (j == 0) ? c2w0 : (j == 1) ? c2w1 : c2w2;
    const float* wp = wj + o*144 + cbase*9 + min(tap,8);
    float f[8];
    #pragma unroll
    for (int e = 0; e < 8; ++e) {
      float v = wp[e*9];
      f[e] = (tap <= 8) ? v : 0.f;
    }
    wf2[tt] = (uint4){ pkh2(f[0],f[1]), pkh2(f[2],f[3]),
                       pkh2(f[4],f[5]), pkh2(f[6],f[7]) };
  }
}

// ---------------- conv1 (+fused sel): 3->16 via MFMA ----------------
__global__ __launch_bounds__(256, 4) void conv1_kernel(
    const float* __restrict__ x, const float* __restrict__ depth,
    const float* __restrict__ fxp, const uint4* __restrict__ wf1,
    const float* __restrict__ bias,
    uint32_t* __restrict__ sel, __half* __restrict__ h1t) {
  __shared__ __align__(16) __half ts[324*24];     // 15552 B  [py][px][c pad 24]
  __shared__ __align__(16) uint4 wlds[15*64];     // 15360 B  B-frags (LDS: invariant)
  __shared__ float dt[324];                       //  1296 B  depth tile (0-filled OOB)
  __shared__ __align__(16) __half hbuf[1024];     //  2048 B  epilogue bounce
  int tid = threadIdx.x;                          // total 34256 B -> 4 blocks/CU
  int lane = tid & 63, wid = tid >> 6;
  int r = lane & 15;
  int tapPar = lane >> 5;
  int c0 = ((lane >> 4) & 1) * 8;
  float bo = bias[r];
  float fx = fxp[0];

  // ---- stage B-frags: coalesced COPY from packed table ----
  #pragma unroll
  for (int it = 0; it < 4; ++it) {
    int t = tid + it*256;
    if (t < 960) wlds[t] = wf1[t];
  }

  int bsw = (blockIdx.x & 7)*196 + (blockIdx.x >> 3);  // XCD swizzle, 1568 = 8*196
  int tbase = bsw * 2;
  float pf[2][3]; float pd[2];
  {
    int tile = tbase;
    int n = tile/196, rem = tile%196, br = rem/14, bc = rem%14;
    int y0 = br*16 - 1, x0 = bc*16 - 1;
    const float* xn = x + (size_t)n*3*HWP;
    const float* dn = depth + (size_t)n*HWP;
    #pragma unroll
    for (int it = 0; it < 2; ++it) {
      int p = min(tid + it*256, 323);
      int yy = y0 + p/18, xx = x0 + p%18;
      int gy = min(max(yy,0),HH-1), gx = min(max(xx,0),HWD-1);
      size_t off = (size_t)gy*HWD + gx;
      pf[it][0] = xn[off]; pf[it][1] = xn[HWP+off]; pf[it][2] = xn[2*HWP+off];
      float dv = dn[off];
      pd[it] = (yy>=0 && yy<HH && xx>=0 && xx<HWD) ? dv : 0.f;  // true 0-pad
    }
  }

  for (int ti = 0; ti < 2; ++ti) {
    int tile = tbase + ti;
    int n = tile/196, rem = tile%196, br = rem/14, bc = rem%14;
    #pragma unroll
    for (int it = 0; it < 2; ++it) {
      int p = tid + it*256;
      if (p < 324) {
        uint4 v0 = { pkh2(pf[it][0], pf[it][1]), pkh2(pf[it][2], 0.f), 0u, 0u };
        uint4 z  = { 0u, 0u, 0u, 0u };
        *(uint4*)(ts + p*24)      = v0;
        *(uint4*)(ts + p*24 + 8)  = z;
        *(uint4*)(ts + p*24 + 16) = z;
        dt[p] = pd[it];
      }
    }
    if (ti < 1) {
      int tile2 = tile + 1;
      int n2 = tile2/196, rem2 = tile2%196, br2 = rem2/14, bc2 = rem2%14;
      int y0 = br2*16 - 1, x0 = bc2*16 - 1;
      const float* xn = x + (size_t)n2*3*HWP;
      const float* dn = depth + (size_t)n2*HWP;
      #pragma unroll
      for (int it = 0; it < 2; ++it) {
        int p = min(tid + it*256, 323);
        int yy = y0 + p/18, xx = x0 + p%18;
        int gy = min(max(yy,0),HH-1), gx = min(max(xx,0),HWD-1);
        size_t off = (size_t)gy*HWD + gx;
        pf[it][0] = xn[off]; pf[it][1] = xn[HWP+off]; pf[it][2] = xn[2*HWP+off];
        float dv = dn[off];
        pd[it] = (yy>=0 && yy<HH && xx>=0 && xx<HWD) ? dv : 0.f;
      }
    }
    __syncthreads();                                 // bar_A: ts/dt (and wlds) ready
    // ---- sel bits: each thread computes its pixel; exchange via intra-wave shfl ----
    uint32_t bits = 0;
    {
      int py = tid >> 4, px = tid & 15;
      float c = dt[(py+1)*18 + (px+1)];
      float gr = c / fx;
      float hf = gr * 0.5f;
      #pragma unroll
      for (int i = 0; i < 3; ++i)
        #pragma unroll
        for (int j = 0; j < 3; ++j) {
          float d = dt[(py+i)*18 + (px+j)];
          int k = i*3 + j;
          uint32_t bb = 0;
          if (fabsf(d - (c + gr)) <= hf) bb |= 1u;
          if (fabsf(d - c) < hf)         bb |= 2u;
          if (fabsf(d - (c - gr)) <= hf) bb |= 4u;
          bits |= bb << (3*k);
        }
      sel[(size_t)n*HWP + (br*16 + py)*HWD + bc*16 + px] = bits;  // for conv2
    }
    uint32_t svc[4];
    #pragma unroll
    for (int ty = 0; ty < 4; ++ty)
      svc[ty] = __shfl(bits, ty*16 + r, 64);         // producer lane ty*16+r, same wave
    // ---- MFMA phase ----
    f32x4 acc[4] = {{0,0,0,0},{0,0,0,0},{0,0,0,0},{0,0,0,0}};
    #pragma unroll
    for (int p = 0; p < 5; ++p) {
      int ta = 2*p, tb = (2*p+1 > 8) ? 8 : 2*p+1;   // tap9 dups tap8 (B=0 kills it)
      int dyL = tapPar ? tb/3 : ta/3;
      int dxL = tapPar ? tb%3 : ta%3;
      int shL = 3*(tapPar ? 2*p+1 : 2*p);
      uint4 a[4];
      #pragma unroll
      for (int ty = 0; ty < 4; ++ty) {
        int ly = wid*4 + ty;
        a[ty] = *(const uint4*)(ts + ((ly + dyL)*18 + (r + dxL))*24 + c0);
      }
      #pragma unroll
      for (int j = 0; j < 3; ++j) {
        uint4 bf = wlds[(p*3 + j)*64 + lane];
        #pragma unroll
        for (int ty = 0; ty < 4; ++ty) {
          uint32_t msk = 0u - ((svc[ty] >> (shL + j)) & 1u);
          uint4 am = { a[ty].x & msk, a[ty].y & msk, a[ty].z & msk, a[ty].w & msk };
          acc[ty] = mfma16(am, bf, acc[ty]);
        }
      }
    }
    // ---- epilogue: relu + channel-last f16 store via hbuf bounce ----
    #pragma unroll
    for (int ty = 0; ty < 4; ++ty) {
      int gy = br*16 + wid*4 + ty;
      #pragma unroll
      for (int e = 0; e < 4; ++e) {
        float v = fmaxf(acc[ty][e] + bo, 0.f);
        hbuf[wid*256 + ((lane>>4)*4 + e)*16 + r] = __float2half(v);
      }
      uint2 hw = *(uint2*)&hbuf[wid*256 + lane*4];
      *(uint2*)(h1t + ((size_t)(n*HWP + gy*HWD) + bc*16)*16 + lane*4) = hw;
    }
    __syncthreads();   // bar_B: ts/dt/hbuf reads done before next tile's writes
  }
}

// ---------------- conv2: 16->16 via MFMA, A-frags DIRECT from global ----------------
__global__ __launch_bounds__(256, 5) void conv2_kernel(
    const __half* __restrict__ h1t, const uint32_t* __restrict__ sel,
    const uint4* __restrict__ wf2, const float* __restrict__ bias,
    __half* __restrict__ pooled) {
  __shared__ __align__(16) uint4 wlds[15*64];     // 15360 B (LDS: invariant)
  __shared__ float pl[64*17];                     //  4352 B -> total 19.7 KB, 5/CU
  int tid = threadIdx.x;
  int lane = tid & 63, wid = tid >> 6;
  int r = lane & 15;
  int tapPar = lane >> 5;
  int c0 = ((lane >> 4) & 1) * 8;
  float bo = bias[r];

  // ---- stage B-frags: coalesced COPY from packed table ----
  #pragma unroll
  for (int it = 0; it < 4; ++it) {
    int t = tid + it*256;
    if (t < 960) wlds[t] = wf2[t];
  }
  __syncthreads();

  int bsw = (blockIdx.x & 7)*196 + (blockIdx.x >> 3);  // same swizzle as conv1
  int tbase = bsw * 2;
  for (int ti = 0; ti < 2; ++ti) {
    int tile = tbase + ti;
    int n = tile/196, rem = tile%196, br = rem/14, bc = rem%14;
    const __half* hn = h1t + (size_t)n*HWP*16;
    uint32_t svc[4];
    #pragma unroll
    for (int ty = 0; ty < 4; ++ty)
      svc[ty] = sel[(size_t)n*HWP + (br*16 + wid*4 + ty)*HWD + bc*16 + r];
    f32x4 acc[4] = {{0,0,0,0},{0,0,0,0},{0,0,0,0},{0,0,0,0}};
    #pragma unroll
    for (int p = 0; p < 5; ++p) {
      int ta = 2*p, tb = (2*p+1 > 8) ? 8 : 2*p+1;
      int dyL = tapPar ? tb/3 : ta/3;
      int dxL = tapPar ? tb%3 : ta%3;
      int shL = 3*(tapPar ? 2*p+1 : 2*p);
      int gx = min(max(bc*16 + r + dxL - 1, 0), HWD-1);
      uint4 a[4];
      #pragma unroll
      for (int ty = 0; ty < 4; ++ty) {
        int gy = min(max(br*16 + wid*4 + ty + dyL - 1, 0), HH-1);
        a[ty] = *(const uint4*)(hn + ((size_t)(gy*HWD + gx))*16 + c0);
      }
      #pragma unroll
      for (int j = 0; j < 3; ++j) {
        uint4 bf = wlds[(p*3 + j)*64 + lane];
        #pragma unroll
        for (int ty = 0; ty < 4; ++ty) {
          uint32_t msk = 0u - ((svc[ty] >> (shL + j)) & 1u);
          uint4 am = { a[ty].x & msk, a[ty].y & msk, a[ty].z & msk, a[ty].w & msk };
          acc[ty] = mfma16(am, bf, acc[ty]);
        }
      }
    }
    #pragma unroll
    for (int yp = 0; yp < 2; ++yp) {
      f32x4 v0 = acc[yp*2], v1 = acc[yp*2+1];
      float m00 = fmaxf(fmaxf(v0[0]+bo, 0.f), fmaxf(v0[1]+bo, 0.f));
      float m01 = fmaxf(fmaxf(v0[2]+bo, 0.f), fmaxf(v0[3]+bo, 0.f));
      float m10 = fmaxf(fmaxf(v1[0]+bo, 0.f), fmaxf(v1[1]+bo, 0.f));
      float m11 = fmaxf(fmaxf(v1[2]+bo, 0.f), fmaxf(v1[3]+bo, 0.f));
      int prow = wid*2 + yp;
      int pc0 = (lane >> 4)*2;
      pl[(prow*8 + pc0)*17 + r]     = fmaxf(m00, m10);
      pl[(prow*8 + pc0 + 1)*17 + r] = fmaxf(m01, m11);
    }
    __syncthreads();   // pl ready
    for (int t = tid; t < 1024; t += 256) {       // repack channel-first f16
      int oo = t >> 6; int pix = t & 63;
      int pr = pix >> 3, pc = pix & 7;
      pooled[(size_t)(n*16 + oo)*PHW + (br*8 + pr)*PW + bc*8 + pc] =
          __float2half(pl[pix*17 + oo]);
    }
    __syncthreads();   // pl reads done before next tile's writes
  }
}

// ---------------- FC1 via MFMA: 16 outputs/block, grid 1568 ----------------
// R23: finer blocks for residency; per-output reduction structure unchanged
// (four 256-k wave-chunks, same order) -> bit-identical partials vs R22.
__global__ __launch_bounds__(256) void fc1_kernel(
    const __half* __restrict__ hin, const float* __restrict__ wgt,
    float* __restrict__ partial) {
  __shared__ __align__(16) f32x4 cacc[256];        //  4 KB
  int tid = threadIdx.x;
  int b = blockIdx.x;
  int snum = (b & 7)*196 + (b >> 3);  // bijective XCD swizzle: 1568 = 8 * 196
  int kseg = snum >> 3;               // 0..195
  int grp  = snum & 7;                // 0..7 -> 8 groups of 16 outputs
  int obase = grp * 16;
  int lane = tid & 63, wid = tid >> 6;
  int row = lane & 15;
  int koct = lane >> 4;               // 0..3 -> k-octet within K=32
  size_t kb = (size_t)kseg*1024 + wid*256 + koct*8;
  const __half* ap  = hin + (size_t)row*FCK + kb;
  const float*  wp0 = wgt + (size_t)(obase + row)*FCK + kb;
  f32x4 acc0 = {0,0,0,0};
  #pragma unroll
  for (int s = 0; s < 8; ++s) {
    uint4 av = *(const uint4*)(ap + s*32);
    float4 wa = *(const float4*)(wp0 + s*32);
    float4 wb = *(const float4*)(wp0 + s*32 + 4);
    uint4 bf0 = { pkh2(wa.x,wa.y), pkh2(wa.z,wa.w), pkh2(wb.x,wb.y), pkh2(wb.z,wb.w) };
    acc0 = mfma16(av, bf0, acc0);
  }
  cacc[wid*64 + lane] = acc0;
  __syncthreads();
  {
    int l = tid & 63, e = tid >> 6;
    int nn = (l >> 4)*4 + e;
    int oo = l & 15;
    float s = cacc[l][e] + cacc[64 + l][e] + cacc[128 + l][e] + cacc[192 + l][e];
    partial[((size_t)kseg*16 + nn)*128 + obase + oo] = s;
  }
}

// ---------------- FC2 (+fused fc1-reduce) + log_softmax, 1024 threads ----------------
__global__ __launch_bounds__(1024) void fc2_kernel(
    const float* __restrict__ partial, const float* __restrict__ fc1b,
    const float* __restrict__ w, const float* __restrict__ b,
    float* __restrict__ out) {
  __shared__ float psum[1024];
  __shared__ float row[128];
  __shared__ float v[10];
  __shared__ float lse;
  int n = blockIdx.x, t = threadIdx.x;
  {
    int o = t & 127, slice = t >> 7;              // 8 slices
    const float* pp = partial + ((size_t)slice*16 + n)*128 + o;
    float s = 0.f;
    for (int k = slice; k < KSEG; k += 8)
      s += pp[(size_t)(k - slice)*2048];
    psum[t] = s;
  }
  __syncthreads();
  if (t < 128) {
    float s = fc1b[t];
    #pragma unroll
    for (int sl = 0; sl < 8; ++sl) s += psum[sl*128 + t];
    row[t] = s;
  }
  __syncthreads();
  {
    int wv = t >> 6, lane = t & 63;
    if (wv < 10) {
      int d = wv;
      float acc = w[d*128 + lane]*row[lane] + w[d*128 + 64 + lane]*row[64 + lane];
      acc += __shfl_xor(acc, 1);  acc += __shfl_xor(acc, 2);
      acc += __shfl_xor(acc, 4);  acc += __shfl_xor(acc, 8);
      acc += __shfl_xor(acc, 16); acc += __shfl_xor(acc, 32);
      if (lane == 0) v[d] = acc + b[d];
    }
  }
  __syncthreads();
  if (t == 0) {
    float m = v[0];
    for (int i = 1; i < 10; ++i) m = fmaxf(m, v[i]);
    float se = 0.f;
    for (int i = 0; i < 10; ++i) se += expf(v[i] - m);
    lse = m + logf(se);
  }
  __syncthreads();
  if (t < 10) out[n*10 + t] = v[t] - lse;
}

extern "C" void kernel_launch(void* const* d_in, const int* in_sizes, int n_in,
                              void* d_out, int out_size, void* d_ws, size_t ws_size,
                              hipStream_t stream) {
  const float* x     = (const float*)d_in[0];
  const float* depth = (const float*)d_in[1];
  const float* fx    = (const float*)d_in[2];
  const float* c1w0  = (const float*)d_in[3];
  const float* c1w1  = (const float*)d_in[4];
  const float* c1w2  = (const float*)d_in[5];
  const float* c1b   = (const float*)d_in[6];
  const float* c2w0  = (const float*)d_in[7];
  const float* c2w1  = (const float*)d_in[8];
  const float* c2w2  = (const float*)d_in[9];
  const float* c2b   = (const float*)d_in[10];
  const float* fc1w  = (const float*)d_in[11];
  const float* fc1b  = (const float*)d_in[12];
  const float* fc2w  = (const float*)d_in[13];
  const float* fc2b  = (const float*)d_in[14];
  float* out = (float*)d_out;

  char* ws = (char*)d_ws;
  uint32_t* sel  = (uint32_t*)ws;                      // 3,211,264 B
  __half* h1t    = (__half*)(ws + 3211264);            // 25,690,112 B
  __half* pooled = (__half*)(ws + 28901376);           //  6,422,528 B
  float* partial = (float*)(ws + 35323904);            //  1,605,632 B
  uint4* wf1     = (uint4*)(ws + 36929536);            //     15,360 B
  uint4* wf2     = (uint4*)(ws + 36944896);            //     15,360 B

  pack_wfrags_kernel<<<8, 256, 0, stream>>>(c1w0, c1w1, c1w2, c2w0, c2w1, c2w2, wf1, wf2);
  conv1_kernel<<<1568, 256, 0, stream>>>(x, depth, fx, wf1, c1b, sel, h1t);
  conv2_kernel<<<1568, 256, 0, stream>>>(h1t, sel, wf2, c2b, pooled);
  fc1_kernel<<<1568, 256, 0, stream>>>(pooled, fc1w, partial);
  fc2_kernel<<<16, 1024, 0, stream>>>(partial, fc1b, fc2w, fc2b, out);
}